// Round 1
// baseline (201.457 us; speedup 1.0000x reference)
//
#include <hip/hip_runtime.h>
#include <hip/hip_bf16.h>

#define N_NODES_K 500000
#define D_FEAT_K 256

// --- monotonic float<->uint encoding for atomicMax on floats -------------
__device__ __forceinline__ unsigned enc_f(float f) {
    unsigned u = __float_as_uint(f);
    return (u & 0x80000000u) ? ~u : (u | 0x80000000u);
}
__device__ __forceinline__ float dec_f(unsigned u) {
    u = (u & 0x80000000u) ? (u & 0x7fffffffu) : ~u;
    return __uint_as_float(u);
}

// --- kernel 0: init max slot + exclusive scan of graph_sizes -------------
__global__ void scan_offsets_kernel(const int* __restrict__ sizes,
                                    int* __restrict__ offsets,
                                    unsigned* __restrict__ maxslot,
                                    int n) {
    __shared__ int lds[1024];
    const int tid = threadIdx.x;
    if (tid == 0) maxslot[0] = 0u;   // below encoding of any real float
    int carry = 0;
    for (int base = 0; base < n; base += 1024) {
        int i = base + tid;
        int v = (i < n) ? sizes[i] : 0;
        lds[tid] = v;
        __syncthreads();
        for (int off = 1; off < 1024; off <<= 1) {
            int t = (tid >= off) ? lds[tid - off] : 0;
            __syncthreads();
            lds[tid] += t;
            __syncthreads();
        }
        int incl = lds[tid];
        if (i < n) offsets[i] = carry + incl - v;   // exclusive prefix
        __syncthreads();
        carry += lds[1023];
        __syncthreads();
    }
}

// --- kernel 1: one wave per node; gate logit + Dense(2) projection -------
// states row = 256 f32 = 64 lanes x float4, perfectly coalesced.
__global__ __launch_bounds__(256, 4)
void pass1_kernel(const float* __restrict__ states,
                  const float* __restrict__ gate_w,
                  const float* __restrict__ gate_b,
                  const float* __restrict__ out_w,
                  float* __restrict__ l,
                  float2* __restrict__ o,
                  unsigned* __restrict__ maxslot,
                  int n_nodes) {
    const int lane = threadIdx.x & 63;
    const int wib  = threadIdx.x >> 6;
    const int wpb  = blockDim.x >> 6;
    const int gwave  = blockIdx.x * wpb + wib;
    const int nwaves = gridDim.x * wpb;

    // per-lane weight slice: features [4*lane, 4*lane+4)
    const float4 gw = *reinterpret_cast<const float4*>(gate_w + 4 * lane);
    float4 ow0, ow1;
    {   // out_w is [256][2] row-major: feature f -> elems 2f (c0), 2f+1 (c1)
        float4 a = *reinterpret_cast<const float4*>(out_w + 8 * lane);
        float4 b = *reinterpret_cast<const float4*>(out_w + 8 * lane + 4);
        ow0 = make_float4(a.x, a.z, b.x, b.z);
        ow1 = make_float4(a.y, a.w, b.y, b.w);
    }
    const float gb = gate_b[0];

    float lmax = -3.0e38f;
    for (int i = gwave; i < n_nodes; i += nwaves) {
        float4 s = *reinterpret_cast<const float4*>(states + (size_t)i * D_FEAT_K + 4 * lane);
        float pl = s.x * gw.x  + s.y * gw.y  + s.z * gw.z  + s.w * gw.w;
        float p0 = s.x * ow0.x + s.y * ow0.y + s.z * ow0.z + s.w * ow0.w;
        float p1 = s.x * ow1.x + s.y * ow1.y + s.z * ow1.z + s.w * ow1.w;
#pragma unroll
        for (int m = 32; m >= 1; m >>= 1) {
            pl += __shfl_xor(pl, m);
            p0 += __shfl_xor(p0, m);
            p1 += __shfl_xor(p1, m);
        }
        if (lane == 0) {
            float li = pl + gb;
            l[i] = li;
            o[i] = make_float2(p0, p1);
            lmax = fmaxf(lmax, li);
        }
    }
    if (lane == 0) atomicMax(maxslot, enc_f(lmax));
}

// --- kernel 2: one wave per graph; softmax-normalize + weighted sum ------
// result[g,c] = (sum_i o_i,c * e_i + b_c * S) / (S + 1e-16), e_i=exp(l_i-M)
__global__ __launch_bounds__(256, 4)
void pass2_kernel(const float* __restrict__ l,
                  const float2* __restrict__ o,
                  const int* __restrict__ offsets,
                  const int* __restrict__ sizes,
                  const float* __restrict__ out_b,
                  const unsigned* __restrict__ maxslot,
                  float2* __restrict__ outp,
                  int n_graphs) {
    const int lane = threadIdx.x & 63;
    const int g = blockIdx.x * (blockDim.x >> 6) + (threadIdx.x >> 6);
    if (g >= n_graphs) return;

    const float M  = dec_f(*maxslot);
    const int  off = offsets[g];
    const int  sz  = sizes[g];

    float se = 0.f, s0 = 0.f, s1 = 0.f;
    for (int j = lane; j < sz; j += 64) {
        float  e  = expf(l[off + j] - M);
        float2 ov = o[off + j];
        se += e;
        s0 += ov.x * e;
        s1 += ov.y * e;
    }
#pragma unroll
    for (int m = 32; m >= 1; m >>= 1) {
        se += __shfl_xor(se, m);
        s0 += __shfl_xor(s0, m);
        s1 += __shfl_xor(s1, m);
    }
    if (lane == 0) {
        const float b0 = out_b[0], b1 = out_b[1];
        const float inv = 1.0f / (se + 1e-16f);
        outp[g] = make_float2((s0 + b0 * se) * inv, (s1 + b1 * se) * inv);
    }
}

extern "C" void kernel_launch(void* const* d_in, const int* in_sizes, int n_in,
                              void* d_out, int out_size, void* d_ws, size_t ws_size,
                              hipStream_t stream) {
    const float* states      = (const float*)d_in[0];
    const int*   graph_sizes = (const int*)d_in[1];
    const float* gate_w      = (const float*)d_in[2];
    const float* gate_b      = (const float*)d_in[3];
    const float* out_w       = (const float*)d_in[4];
    const float* out_b       = (const float*)d_in[5];

    const int n_nodes  = in_sizes[0] / D_FEAT_K;   // 500000
    const int n_graphs = in_sizes[1];              // 10000

    // workspace layout (bytes):
    //   [0, 4*n_nodes)                      : l   (gate logits, f32)
    //   [4*n_nodes, 4*n_nodes + 8*n_nodes)  : o   (float2 projections)
    //   then offsets (int[n_graphs]), then maxslot (uint)
    char* ws = (char*)d_ws;
    float*    l_buf   = (float*)ws;
    float2*   o_buf   = (float2*)(ws + (size_t)4 * n_nodes);
    int*      offsets = (int*)(ws + (size_t)12 * n_nodes);
    unsigned* maxslot = (unsigned*)(ws + (size_t)12 * n_nodes + (size_t)4 * n_graphs);

    // 0) offsets + maxslot init (single block)
    scan_offsets_kernel<<<1, 1024, 0, stream>>>(graph_sizes, offsets, maxslot, n_graphs);

    // 1) per-node logits + projections + global max (one wave per node)
    {
        const int block = 256;                 // 4 waves
        const int grid  = 2048;                // grid-stride, ~61 nodes/wave
        pass1_kernel<<<grid, block, 0, stream>>>(states, gate_w, gate_b, out_w,
                                                 l_buf, o_buf, maxslot, n_nodes);
    }

    // 2) per-graph softmax + gated sum (one wave per graph)
    {
        const int block = 256;                 // 4 waves = 4 graphs/block
        const int grid  = (n_graphs + 3) / 4;
        pass2_kernel<<<grid, block, 0, stream>>>(l_buf, o_buf, offsets, graph_sizes,
                                                 out_b, maxslot, (float2*)d_out, n_graphs);
    }
}

// Round 2
// 109.926 us; speedup vs baseline: 1.8327x; 1.8327x over previous
//
#include <hip/hip_runtime.h>
#include <hip/hip_bf16.h>

#define D_FEAT_K 256

// --- kernel 0: exclusive prefix scan of graph_sizes (one block, shuffle-based)
__global__ void scan_kernel(const int* __restrict__ sizes,
                            int* __restrict__ offsets,
                            int n) {
    __shared__ int wsum[16];
    __shared__ int chunk_carry;
    const int tid  = threadIdx.x;
    const int lane = tid & 63;
    const int wid  = tid >> 6;
    if (tid == 0) chunk_carry = 0;
    __syncthreads();
    for (int base = 0; base < n; base += 1024) {
        const int i = base + tid;
        const int v = (i < n) ? sizes[i] : 0;
        int s = v;
        // inclusive wave scan
#pragma unroll
        for (int d = 1; d < 64; d <<= 1) {
            int t = __shfl_up(s, d);
            if (lane >= d) s += t;
        }
        if (lane == 63) wsum[wid] = s;
        __syncthreads();
        if (wid == 0 && lane < 16) {
            int w = wsum[lane];
#pragma unroll
            for (int d = 1; d < 16; d <<= 1) {
                int t = __shfl_up(w, d);
                if (lane >= d) w += t;
            }
            wsum[lane] = w;   // inclusive wave-sum scan
        }
        __syncthreads();
        const int waveoff = (wid == 0) ? 0 : wsum[wid - 1];
        if (i < n) offsets[i] = chunk_carry + waveoff + s - v;  // exclusive
        const int total = wsum[15];
        __syncthreads();
        if (tid == 0) chunk_carry += total;
        __syncthreads();
    }
}

// --- kernel 1: fully fused — one wave-block per graph --------------------
// result[g,c] = (sum_i o_i,c * e_i + b_c * S) / (S + 1e-16), e_i = exp(l_i)
// (global-max subtraction cancels algebraically; eps term shift ~1e-14)
// Layout: 16 lanes per row, 4 rows per wave iteration.
__global__ __launch_bounds__(64)
void fused_kernel(const float* __restrict__ states,
                  const float* __restrict__ gate_w,
                  const float* __restrict__ gate_b,
                  const float* __restrict__ out_w,
                  const float* __restrict__ out_b,
                  const int* __restrict__ offsets,
                  const int* __restrict__ sizes,
                  float2* __restrict__ outp,
                  int n_graphs) {
    const int g = blockIdx.x;
    if (g >= n_graphs) return;
    const int lane = threadIdx.x;   // 0..63
    const int q    = lane & 15;     // lane within row
    const int grp  = lane >> 4;     // which of 4 rows per iteration

    // per-lane weight slices: features f = 4q + 64k + j, k=0..3, j=0..3
    float4 gw[4], owA[4], owB[4];
#pragma unroll
    for (int k = 0; k < 4; ++k) {
        const int f0 = 4 * q + 64 * k;
        gw[k]  = *reinterpret_cast<const float4*>(gate_w + f0);
        // out_w is [256][2] row-major: (f,c) at 2f+c
        owA[k] = *reinterpret_cast<const float4*>(out_w + 2 * f0);       // c0(f),c1(f),c0(f+1),c1(f+1)
        owB[k] = *reinterpret_cast<const float4*>(out_w + 2 * f0 + 4);   // c0(f+2),c1(f+2),c0(f+3),c1(f+3)
    }
    const float gb  = gate_b[0];
    const int   off = offsets[g];
    const int   sz  = sizes[g];

    float se = 0.f, s0 = 0.f, s1 = 0.f;
    for (int r = grp; r < sz; r += 4) {
        const float* row = states + (size_t)(off + r) * D_FEAT_K;
        float pl = 0.f, p0 = 0.f, p1 = 0.f;
#pragma unroll
        for (int k = 0; k < 4; ++k) {
            float4 s = *reinterpret_cast<const float4*>(row + 4 * q + 64 * k);
            pl += s.x * gw[k].x  + s.y * gw[k].y  + s.z * gw[k].z  + s.w * gw[k].w;
            p0 += s.x * owA[k].x + s.y * owA[k].z + s.z * owB[k].x + s.w * owB[k].z;
            p1 += s.x * owA[k].y + s.y * owA[k].w + s.z * owB[k].y + s.w * owB[k].w;
        }
        // reduce across the 16 lanes of this row (stays within the group)
#pragma unroll
        for (int m = 8; m >= 1; m >>= 1) {
            pl += __shfl_xor(pl, m);
            p0 += __shfl_xor(p0, m);
            p1 += __shfl_xor(p1, m);
        }
        if (q == 0) {
            const float e = expf(pl + gb);
            se += e;
            s0 += p0 * e;
            s1 += p1 * e;
        }
    }
    // combine the 4 group leaders (lanes 0,16,32,48; others hold zeros)
    se += __shfl_xor(se, 16); s0 += __shfl_xor(s0, 16); s1 += __shfl_xor(s1, 16);
    se += __shfl_xor(se, 32); s0 += __shfl_xor(s0, 32); s1 += __shfl_xor(s1, 32);
    if (lane == 0) {
        const float inv = 1.0f / (se + 1e-16f);
        outp[g] = make_float2((s0 + out_b[0] * se) * inv,
                              (s1 + out_b[1] * se) * inv);
    }
}

extern "C" void kernel_launch(void* const* d_in, const int* in_sizes, int n_in,
                              void* d_out, int out_size, void* d_ws, size_t ws_size,
                              hipStream_t stream) {
    const float* states      = (const float*)d_in[0];
    const int*   graph_sizes = (const int*)d_in[1];
    const float* gate_w      = (const float*)d_in[2];
    const float* gate_b      = (const float*)d_in[3];
    const float* out_w       = (const float*)d_in[4];
    const float* out_b       = (const float*)d_in[5];

    const int n_graphs = in_sizes[1];              // 10000

    int* offsets = (int*)d_ws;

    scan_kernel<<<1, 1024, 0, stream>>>(graph_sizes, offsets, n_graphs);

    fused_kernel<<<n_graphs, 64, 0, stream>>>(states, gate_w, gate_b,
                                              out_w, out_b,
                                              offsets, graph_sizes,
                                              (float2*)d_out, n_graphs);
}

// Round 4
// 92.830 us; speedup vs baseline: 2.1702x; 1.1842x over previous
//
#include <hip/hip_runtime.h>
#include <hip/hip_bf16.h>

#define D_FEAT_K 256

typedef float floatx4 __attribute__((ext_vector_type(4)));

// --- kernel 0: exclusive prefix scan of graph_sizes (one block, shuffle-based)
__global__ void scan_kernel(const int* __restrict__ sizes,
                            int* __restrict__ offsets,
                            int n) {
    __shared__ int wsum[16];
    __shared__ int chunk_carry;
    const int tid  = threadIdx.x;
    const int lane = tid & 63;
    const int wid  = tid >> 6;
    if (tid == 0) chunk_carry = 0;
    __syncthreads();
    for (int base = 0; base < n; base += 1024) {
        const int i = base + tid;
        const int v = (i < n) ? sizes[i] : 0;
        int s = v;
#pragma unroll
        for (int d = 1; d < 64; d <<= 1) {
            int t = __shfl_up(s, d);
            if (lane >= d) s += t;
        }
        if (lane == 63) wsum[wid] = s;
        __syncthreads();
        if (wid == 0 && lane < 16) {
            int w = wsum[lane];
#pragma unroll
            for (int d = 1; d < 16; d <<= 1) {
                int t = __shfl_up(w, d);
                if (lane >= d) w += t;
            }
            wsum[lane] = w;
        }
        __syncthreads();
        const int waveoff = (wid == 0) ? 0 : wsum[wid - 1];
        if (i < n) offsets[i] = chunk_carry + waveoff + s - v;  // exclusive
        const int total = wsum[15];
        __syncthreads();
        if (tid == 0) chunk_carry += total;
        __syncthreads();
    }
}

// --- kernel 1: fully fused — one WAVE per graph, 4 waves per block -------
// result[g,c] = (sum_i o_i,c*e_i + b_c*S) / (S + 1e-16), e_i = exp(l_i)
// (global-max subtraction cancels algebraically; eps-term shift ~1e-14)
// 16 lanes per row, 4 rows per wave iteration. Only the gate logit is
// reduced per row; o-projection partials accumulate per-lane and are
// reduced ONCE per graph (deferred-reduction).
__global__ __launch_bounds__(256)
void fused_kernel(const float* __restrict__ states,
                  const float* __restrict__ gate_w,
                  const float* __restrict__ gate_b,
                  const float* __restrict__ out_w,
                  const float* __restrict__ out_b,
                  const int* __restrict__ offsets,
                  const int* __restrict__ sizes,
                  float2* __restrict__ outp,
                  int n_graphs) {
    const int wid  = threadIdx.x >> 6;
    const int lane = threadIdx.x & 63;
    const int g = blockIdx.x * 4 + wid;
    if (g >= n_graphs) return;          // whole-wave exit; no block syncs used

    const int q   = lane & 15;          // lane within row
    const int grp = lane >> 4;          // which of 4 rows per iteration

    // per-lane weight slices: features f = 4q + 64k + j, k=0..3, j=0..3
    float4 gw[4], owA[4], owB[4];
#pragma unroll
    for (int k = 0; k < 4; ++k) {
        const int f0 = 4 * q + 64 * k;
        gw[k]  = *reinterpret_cast<const float4*>(gate_w + f0);
        // out_w is [256][2] row-major: (f,c) at 2f+c
        owA[k] = *reinterpret_cast<const float4*>(out_w + 2 * f0);       // c0(f),c1(f),c0(f+1),c1(f+1)
        owB[k] = *reinterpret_cast<const float4*>(out_w + 2 * f0 + 4);   // c0(f+2),c1(f+2),c0(f+3),c1(f+3)
    }
    const float gb  = gate_b[0];
    const int   off = offsets[g];
    const int   sz  = sizes[g];

    float se = 0.f, s0 = 0.f, s1 = 0.f;   // per-lane accumulators
    for (int r = grp; r < sz; r += 4) {
        const float* row = states + (size_t)(off + r) * D_FEAT_K;
        float pl = 0.f, p0 = 0.f, p1 = 0.f;
#pragma unroll
        for (int k = 0; k < 4; ++k) {
            floatx4 s = __builtin_nontemporal_load(
                reinterpret_cast<const floatx4*>(row + 4 * q + 64 * k));
            pl += s.x * gw[k].x  + s.y * gw[k].y  + s.z * gw[k].z  + s.w * gw[k].w;
            p0 += s.x * owA[k].x + s.y * owA[k].z + s.z * owB[k].x + s.w * owB[k].z;
            p1 += s.x * owA[k].y + s.y * owA[k].w + s.z * owB[k].y + s.w * owB[k].w;
        }
        // reduce gate logit across the 16 lanes of this row; butterfly
        // leaves the full sum in every lane of the group
#pragma unroll
        for (int m = 8; m >= 1; m >>= 1) pl += __shfl_xor(pl, m);
        const float e = expf(pl + gb);  // redundantly in all 16 lanes (VALU)
        se += e;                        // identical within group -> 16x, fixed below
        s0 += p0 * e;                   // per-lane partial of sum_i o0_i*e_i
        s1 += p1 * e;
    }
    // single final reduction across all 64 lanes
#pragma unroll
    for (int m = 32; m >= 1; m >>= 1) {
        se += __shfl_xor(se, m);
        s0 += __shfl_xor(s0, m);
        s1 += __shfl_xor(s1, m);
    }
    if (lane == 0) {
        const float S   = se * 0.0625f;          // undo exact 16x overcount
        const float inv = 1.0f / (S + 1e-16f);
        outp[g] = make_float2((s0 + out_b[0] * S) * inv,
                              (s1 + out_b[1] * S) * inv);
    }
}

extern "C" void kernel_launch(void* const* d_in, const int* in_sizes, int n_in,
                              void* d_out, int out_size, void* d_ws, size_t ws_size,
                              hipStream_t stream) {
    const float* states      = (const float*)d_in[0];
    const int*   graph_sizes = (const int*)d_in[1];
    const float* gate_w      = (const float*)d_in[2];
    const float* gate_b      = (const float*)d_in[3];
    const float* out_w       = (const float*)d_in[4];
    const float* out_b       = (const float*)d_in[5];

    const int n_graphs = in_sizes[1];              // 10000

    int* offsets = (int*)d_ws;

    scan_kernel<<<1, 1024, 0, stream>>>(graph_sizes, offsets, n_graphs);

    fused_kernel<<<(n_graphs + 3) / 4, 256, 0, stream>>>(
        states, gate_w, gate_b, out_w, out_b,
        offsets, graph_sizes, (float2*)d_out, n_graphs);
}

// Round 5
// 89.254 us; speedup vs baseline: 2.2571x; 1.0401x over previous
//
#include <hip/hip_runtime.h>
#include <hip/hip_bf16.h>

#define D_FEAT_K 256

typedef float floatx4 __attribute__((ext_vector_type(4)));

// --- fully fused, single dispatch — one WAVE per graph, 4 waves/block ----
// result[g,c] = (sum_i o_i,c*e_i + b_c*S) / (S + 1e-16), e_i = exp(l_i)
// (global-max subtraction cancels algebraically; eps-term shift ~1e-14)
//
// Each wave computes its own exclusive offset by summing sizes[0..g) with
// int4 loads (40 KB array -> L1/L2-resident; overlapped with other waves'
// HBM streaming). Then: 16 lanes per row, 4 rows per wave iteration; only
// the gate logit is reduced per row, o-projection partials accumulate
// per-lane and are reduced once per graph.
__global__ __launch_bounds__(256)
void fused_kernel(const float* __restrict__ states,
                  const int* __restrict__ sizes,
                  const float* __restrict__ gate_w,
                  const float* __restrict__ gate_b,
                  const float* __restrict__ out_w,
                  const float* __restrict__ out_b,
                  float2* __restrict__ outp,
                  int n_graphs) {
    const int wid  = threadIdx.x >> 6;
    const int lane = threadIdx.x & 63;
    const int g = blockIdx.x * 4 + wid;
    if (g >= n_graphs) return;          // whole-wave exit; no block syncs used

    // --- self-scan: off = sum(sizes[0..g)), redundantly per wave ---------
    int acc = 0;
    {
        const int nv = g >> 2;          // number of full int4 groups
        const int4* s4 = reinterpret_cast<const int4*>(sizes);
        for (int j = lane; j < nv; j += 64) {
            int4 v = s4[j];
            acc += v.x + v.y + v.z + v.w;
        }
        for (int j = (nv << 2) + lane; j < g; j += 64) acc += sizes[j];
#pragma unroll
        for (int m = 32; m >= 1; m >>= 1) acc += __shfl_xor(acc, m);
    }
    const int off = acc;
    const int sz  = sizes[g];

    const int q   = lane & 15;          // lane within row
    const int grp = lane >> 4;          // which of 4 rows per iteration

    // per-lane weight slices: features f = 4q + 64k + j, k=0..3, j=0..3
    float4 gw[4], owA[4], owB[4];
#pragma unroll
    for (int k = 0; k < 4; ++k) {
        const int f0 = 4 * q + 64 * k;
        gw[k]  = *reinterpret_cast<const float4*>(gate_w + f0);
        // out_w is [256][2] row-major: (f,c) at 2f+c
        owA[k] = *reinterpret_cast<const float4*>(out_w + 2 * f0);       // c0(f),c1(f),c0(f+1),c1(f+1)
        owB[k] = *reinterpret_cast<const float4*>(out_w + 2 * f0 + 4);   // c0(f+2),c1(f+2),c0(f+3),c1(f+3)
    }
    const float gb = gate_b[0];

    float se = 0.f, s0 = 0.f, s1 = 0.f;   // per-lane accumulators
    for (int r = grp; r < sz; r += 4) {
        const float* row = states + (size_t)(off + r) * D_FEAT_K;
        float pl = 0.f, p0 = 0.f, p1 = 0.f;
#pragma unroll
        for (int k = 0; k < 4; ++k) {
            floatx4 s = __builtin_nontemporal_load(
                reinterpret_cast<const floatx4*>(row + 4 * q + 64 * k));
            pl += s.x * gw[k].x  + s.y * gw[k].y  + s.z * gw[k].z  + s.w * gw[k].w;
            p0 += s.x * owA[k].x + s.y * owA[k].z + s.z * owB[k].x + s.w * owB[k].z;
            p1 += s.x * owA[k].y + s.y * owA[k].w + s.z * owB[k].y + s.w * owB[k].w;
        }
        // reduce gate logit across the 16 lanes of this row; butterfly
        // leaves the full sum in every lane of the group
#pragma unroll
        for (int m = 8; m >= 1; m >>= 1) pl += __shfl_xor(pl, m);
        const float e = __expf(pl + gb);  // redundantly in all 16 lanes
        se += e;                          // identical within group -> 16x, fixed below
        s0 += p0 * e;                     // per-lane partial of sum_i o0_i*e_i
        s1 += p1 * e;
    }
    // single final reduction across all 64 lanes
#pragma unroll
    for (int m = 32; m >= 1; m >>= 1) {
        se += __shfl_xor(se, m);
        s0 += __shfl_xor(s0, m);
        s1 += __shfl_xor(s1, m);
    }
    if (lane == 0) {
        const float S   = se * 0.0625f;          // undo exact 16x overcount
        const float inv = 1.0f / (S + 1e-16f);
        outp[g] = make_float2((s0 + out_b[0] * S) * inv,
                              (s1 + out_b[1] * S) * inv);
    }
}

extern "C" void kernel_launch(void* const* d_in, const int* in_sizes, int n_in,
                              void* d_out, int out_size, void* d_ws, size_t ws_size,
                              hipStream_t stream) {
    const float* states      = (const float*)d_in[0];
    const int*   graph_sizes = (const int*)d_in[1];
    const float* gate_w      = (const float*)d_in[2];
    const float* gate_b      = (const float*)d_in[3];
    const float* out_w       = (const float*)d_in[4];
    const float* out_b       = (const float*)d_in[5];

    const int n_graphs = in_sizes[1];              // 10000

    fused_kernel<<<(n_graphs + 3) / 4, 256, 0, stream>>>(
        states, graph_sizes, gate_w, gate_b, out_w, out_b,
        (float2*)d_out, n_graphs);
}